// Round 3
// baseline (612.535 us; speedup 1.0000x reference)
//
#include <hip/hip_runtime.h>

// EncoderALSTM: T=128, B=32, H=256, I=256, 4H=1024.
// Round-10: RAW-H EXCHANGE. 8 blocks per batch (m-slice 32 dims) as round-8,
// but the inter-block protocol now exchanges ONLY the raw h-slices
// (16 tagged u64 = 128B per producer per step). Consumers assemble full h(t-1),
// then compute scores (vs full fp16 history in LDS, swizzled), y/w rows
// (register-resident Wa row per thread, full 256-dim f32-accum dots), softmax,
// z-scan over fp16 y-history, h', gates (register Whh), cell — all locally.
// Replaces ywp(2048)+psx(512) tagged-u64 exchange + 8-line-per-thread polling
// with 128 single-u64 polls. Precision: no more fp16 partial-sum rounding.
// 6 barriers/step. Zero fences.
//
// ws layout (bytes):
//   gih      @0         16,777,216  fp32 [t*32+b][1024]
//   W_ihT    @16777216   1,048,576  fp32 (for compute_gih)
//   Whh_pack @17825792     524,288  uint4 [8 m][512 thr][8]
//   WaRow    @18350080     262,144  uint4 [2 type][256 j][32]  (type0: ctx cols, type1: h cols)
//   hx       @18612224      32,768  u64 [32 b][8 m][16] tagged h-slice pairs

#define T_DIM 128
#define B_DIM 32

typedef _Float16 half2_t __attribute__((ext_vector_type(2)));

static __device__ __forceinline__ unsigned pack2(float a, float b) {
  half2_t h;
  h.x = (_Float16)a;
  h.y = (_Float16)b;
  return __builtin_bit_cast(unsigned, h);
}

static __device__ __forceinline__ float dot2f(unsigned w, unsigned v, float acc) {
  half2_t a = __builtin_bit_cast(half2_t, w);
  half2_t b = __builtin_bit_cast(half2_t, v);
#if __has_builtin(__builtin_amdgcn_fdot2)
  return __builtin_amdgcn_fdot2(a, b, acc, false);
#else
  return acc + (float)a.x * (float)b.x + (float)a.y * (float)b.y;
#endif
}

static __device__ __forceinline__ float dot8(uint4 w, uint4 v, float acc) {
  acc = dot2f(w.x, v.x, acc);
  acc = dot2f(w.y, v.y, acc);
  acc = dot2f(w.z, v.z, acc);
  acc = dot2f(w.w, v.w, acc);
  return acc;
}

static __device__ __forceinline__ float lo16(unsigned u) {
  return (float)__builtin_bit_cast(half2_t, u).x;
}
static __device__ __forceinline__ float hi16(unsigned u) {
  return (float)__builtin_bit_cast(half2_t, u).y;
}

static __device__ __forceinline__ float fsig(float x) {
  return __builtin_amdgcn_rcpf(1.f + __expf(-x));
}
static __device__ __forceinline__ float ftanh(float x) {
  float e = __expf(2.f * x);
  return 1.f - 2.f * __builtin_amdgcn_rcpf(e + 1.f);
}

// ---------------- kernel 0: pack weights + zero tag buffer ----------------
__global__ void pack_weights(const float* __restrict__ W_ih, const float* __restrict__ W_hh,
                             const float* __restrict__ W_a, float* __restrict__ W_ihT,
                             uint4* __restrict__ Whh_pack, uint4* __restrict__ WaRow,
                             unsigned long long* __restrict__ hx) {
  int n = blockIdx.x * 256 + threadIdx.x;  // 0..262143
  {  // W_ihT[k][r] = W_ih[r][k]
    int k = n >> 10, r = n & 1023;
    W_ihT[n] = W_ih[r * 256 + k];
  }
  if (n < 32768) {  // Whh_pack[m][tid][i]: W_hh[r][(4i+qk)*8 ..+8]  (m-slice 32 dims)
    int m = n >> 12, tid = (n >> 3) & 511, i = n & 7;
    int r_local = tid >> 2, qk = tid & 3;
    int q = r_local >> 5, jl = r_local & 31;
    int r = q * 256 + m * 32 + jl;
    const float* src = W_hh + r * 256 + (4 * i + qk) * 8;
    uint4 v;
    v.x = pack2(src[0], src[1]);
    v.y = pack2(src[2], src[3]);
    v.z = pack2(src[4], src[5]);
    v.w = pack2(src[6], src[7]);
    Whh_pack[n] = v;
  }
  if (n < 16384) {  // WaRow[type][j][i]: 8 cols at W_a[j][type*256 + i*8]
    int type = n >> 13, j = (n >> 5) & 255, i = n & 31;
    const float* src = W_a + j * 512 + type * 256 + i * 8;
    uint4 v;
    v.x = pack2(src[0], src[1]);
    v.y = pack2(src[2], src[3]);
    v.z = pack2(src[4], src[5]);
    v.w = pack2(src[6], src[7]);
    WaRow[n] = v;
  }
  if (n < 4096)
    __hip_atomic_store(&hx[n], 0ull, __ATOMIC_RELAXED, __HIP_MEMORY_SCOPE_AGENT);
}

// ---------------- kernel 1: gih = embs @ W_ih^T + b_ih + b_hh ----------------
__global__ void compute_gih(const float* __restrict__ embs, const float* __restrict__ W_ihT,
                            const float* __restrict__ b_ih, const float* __restrict__ b_hh,
                            float* __restrict__ gih) {
  __shared__ float embS[8][256];
  const int tid = threadIdx.x;     // 256 threads
  const int tb0 = blockIdx.x * 8;  // 512 blocks x 8 (t,b) pairs
#pragma unroll
  for (int e = 0; e < 8; ++e) embS[e][tid] = embs[(size_t)(tb0 + e) * 256 + tid];
  __syncthreads();
  float acc[8][4];
#pragma unroll
  for (int e = 0; e < 8; ++e)
#pragma unroll
    for (int q = 0; q < 4; ++q) acc[e][q] = 0.f;
  for (int k = 0; k < 256; ++k) {
    float w0 = W_ihT[k * 1024 + tid];
    float w1 = W_ihT[k * 1024 + tid + 256];
    float w2 = W_ihT[k * 1024 + tid + 512];
    float w3 = W_ihT[k * 1024 + tid + 768];
#pragma unroll
    for (int e = 0; e < 8; ++e) {
      float x = embS[e][k];
      acc[e][0] += x * w0;
      acc[e][1] += x * w1;
      acc[e][2] += x * w2;
      acc[e][3] += x * w3;
    }
  }
#pragma unroll
  for (int q = 0; q < 4; ++q) {
    float bias = b_ih[q * 256 + tid] + b_hh[q * 256 + tid];
#pragma unroll
    for (int e = 0; e < 8; ++e)
      gih[(size_t)(tb0 + e) * 1024 + q * 256 + tid] = acc[e][q] + bias;
  }
}

// ---------------- kernel 2: recurrent, raw-h exchange ----------------
__global__ void __launch_bounds__(512, 2)
alstm_rec(const int* __restrict__ lens, const float* __restrict__ gih,
          const uint4* __restrict__ Whh_pack, const uint4* __restrict__ WaRow,
          const float* __restrict__ b_a, unsigned long long* __restrict__ hx,
          float* __restrict__ out, float* __restrict__ hfin, float* __restrict__ cfin) {
  const int tid = threadIdx.x;  // 512 threads
  const int b = blockIdx.x & 31;
  const int m = blockIdx.x >> 5;  // 0..7

  // full fp16 history of h (pairs), XOR-swizzled cols: store [row][col ^ ((row&7)<<2)]
  __shared__ __align__(16) unsigned histF[128 * 128];  // 64 KB
  __shared__ __align__(16) unsigned ystore[128 * 128]; // 64 KB fp16 y-history pairs
  __shared__ __align__(16) unsigned hcur[128];         // assembled h(t-1) pairs
  __shared__ __align__(16) float sc[128];              // raw scores -> alpha
  __shared__ __align__(16) float zp[8][256];           // z partials (8 s-phases)
  __shared__ __align__(16) float wsl[256];             // w_j = Wa_h[j].h
  __shared__ __align__(16) unsigned hp2[128];          // h' pairs
  __shared__ float gsl[128];                           // gates for own 32-dim slice

  // ---- register-resident weights ----
  uint4 wh4[8];
  {
    const uint4* p = Whh_pack + ((size_t)m * 512 + tid) * 8;
#pragma unroll
    for (int i = 0; i < 8; ++i) wh4[i] = p[i];
  }
  uint4 wa[32];  // full 256-dim Wa row: thread = (j = tid&255, type = tid>>8)
  {
    const uint4* p = WaRow + ((size_t)(tid >> 8) * 256 + (tid & 255)) * 32;
#pragma unroll
    for (int i = 0; i < 32; ++i) wa[i] = p[i];
  }
  const float ba_j = (tid < 256) ? b_a[tid] : 0.f;
  const int len_b = lens[b];
  const int r_local = tid >> 2, qk = tid & 3;
  const int gq = r_local >> 5, gjl = r_local & 31;

  if (tid < 128) hp2[tid] = 0u;
  float c_reg = 0.f;  // replicated per-lane (sl = tid&31), consistent across waves
  __syncthreads();

  for (int t = 0; t < T_DIM; ++t) {
    float gih_v = gih[((size_t)t * 32 + b) * 1024 + gq * 256 + m * 32 + gjl];

    if (t > 0) {
      // ---- P0: poll full h(t-1): one tagged u64 per thread (tid<128) ----
      if (tid < 128) {
        const unsigned long long* myhx = hx + b * 128 + tid;
        unsigned long long v;
        for (;;) {
          v = __hip_atomic_load(myhx, __ATOMIC_RELAXED, __HIP_MEMORY_SCOPE_AGENT);
          if ((unsigned)v == (unsigned)t) break;
          __builtin_amdgcn_s_sleep(1);
        }
        unsigned pr = (unsigned)(v >> 32);
        hcur[tid] = pr;
        histF[(t - 1) * 128 + (tid ^ (((t - 1) & 7) << 2))] = pr;
      }
      __syncthreads();  // B0: h(t-1) + hist row t-1 ready
      // ---- P1: scores s<t (4 threads per s, quarter dims each) ----
      if (r_local < t) {
        const int sxz = (r_local & 7) << 2;
        const int srow = r_local * 128;
        const int cb = qk * 32;
        float a0 = 0.f, a1 = 0.f;
#pragma unroll
        for (int k = 0; k < 8; k += 2) {
          uint4 u0 = *(const uint4*)&histF[srow + ((cb + 4 * k) ^ sxz)];
          uint4 u1 = *(const uint4*)&histF[srow + ((cb + 4 * (k + 1)) ^ sxz)];
          uint4 q0 = *(const uint4*)&hcur[cb + 4 * k];
          uint4 q1 = *(const uint4*)&hcur[cb + 4 * (k + 1)];
          a0 = dot8(u0, q0, a0);
          a1 = dot8(u1, q1, a1);
        }
        float a = a0 + a1;
        a += __shfl_xor(a, 1);
        a += __shfl_xor(a, 2);
        if (qk == 0) sc[r_local] = a;
      }
      __syncthreads();  // B1: raw scores ready
      // ---- P2: y/w rows (all 512 threads) then softmax (wave 4) ----
      {
        float a0 = 0.f, a1 = 0.f, a2 = 0.f, a3 = 0.f;
#pragma unroll
        for (int i = 0; i < 32; i += 4) {
          uint4 h0 = *(const uint4*)&hcur[4 * i];
          uint4 h1 = *(const uint4*)&hcur[4 * i + 4];
          uint4 h2 = *(const uint4*)&hcur[4 * i + 8];
          uint4 h3 = *(const uint4*)&hcur[4 * i + 12];
          a0 = dot8(wa[i], h0, a0);
          a1 = dot8(wa[i + 1], h1, a1);
          a2 = dot8(wa[i + 2], h2, a2);
          a3 = dot8(wa[i + 3], h3, a3);
        }
        float val = (a0 + a1) + (a2 + a3);
        if (tid < 256) {  // y_j(t-1): store fp16 pair to y-history
          float o = __shfl_xor(val, 1);
          if (!(tid & 1)) ystore[(t - 1) * 128 + (tid >> 1)] = pack2(val, o);
        } else {  // w_j
          wsl[tid - 256] = val;
        }
      }
      if (tid >= 256 && tid < 320) {  // fused softmax over s in [0,t), wave 4
        const int p = tid - 256;
        float v0 = (p < t) ? sc[p] : -3.0e38f;
        float v1 = (p + 64 < t) ? sc[p + 64] : -3.0e38f;
        float mx = fmaxf(v0, v1);
#pragma unroll
        for (int off = 32; off >= 1; off >>= 1) mx = fmaxf(mx, __shfl_xor(mx, off));
        float e0 = (p < t) ? __expf(v0 - mx) : 0.f;
        float e1 = (p + 64 < t) ? __expf(v1 - mx) : 0.f;
        float sm = e0 + e1;
#pragma unroll
        for (int off = 32; off >= 1; off >>= 1) sm += __shfl_xor(sm, off);
        float inv = __builtin_amdgcn_rcpf(sm);
        sc[p] = e0 * inv;
        sc[p + 64] = e1 * inv;
      }
      __syncthreads();  // B2: alpha + y row t-1 + wsl ready
      // ---- P3: z-scan over fp16 y-history ----
      {
        const int sp = tid >> 6, cg = tid & 63;
        float c0 = 0.f, c1 = 0.f, c2 = 0.f, c3 = 0.f;
        for (int s = sp; s < t; s += 8) {
          float al = sc[s];
          uint2 u = *(const uint2*)&ystore[s * 128 + 2 * cg];
          c0 += al * lo16(u.x);
          c1 += al * hi16(u.x);
          c2 += al * lo16(u.y);
          c3 += al * hi16(u.y);
        }
        float4 st;
        st.x = c0;
        st.y = c1;
        st.z = c2;
        st.w = c3;
        *(float4*)&zp[sp][4 * cg] = st;
      }
      __syncthreads();  // B3: zp ready
      // ---- P4: h'_j = tanh(ba + w + z) ----
      if (tid < 256) {
        float z = 0.f;
#pragma unroll
        for (int p = 0; p < 8; ++p) z += zp[p][tid];
        float hv = ftanh(ba_j + wsl[tid] + z);
        float o = __shfl_xor(hv, 1);
        if (!(tid & 1)) hp2[tid >> 1] = pack2(hv, o);
      }
      __syncthreads();  // B4: hp2 ready
    }
    // ---- P5: gates row r_local, chunks c==qk (mod 4); 2 independent chains ----
    {
      float a0 = 0.f, a1 = 0.f;
#pragma unroll
      for (int i = 0; i < 8; i += 2) {
        uint4 hv0 = *(const uint4*)&hp2[(4 * i + qk) << 2];
        uint4 hv1 = *(const uint4*)&hp2[(4 * (i + 1) + qk) << 2];
        a0 = dot8(wh4[i], hv0, a0);
        a1 = dot8(wh4[i + 1], hv1, a1);
      }
      float a = a0 + a1;
      a += __shfl_xor(a, 1);
      a += __shfl_xor(a, 2);
      if (qk == 0) gsl[r_local] = a + gih_v;
    }
    __syncthreads();  // B5: gsl ready
    // ---- P6: cell redundant in every wave; wave 6 stores + publishes ----
    {
      const int sl = tid & 31;
      float ig = fsig(gsl[sl]);
      float fg = fsig(gsl[32 + sl]);
      float gg = ftanh(gsl[64 + sl]);
      float og = fsig(gsl[96 + sl]);
      float cn = fg * c_reg + ig * gg;
      float hn = og * ftanh(cn);
      c_reg = cn;
      float o = __shfl_xor(hn, 1);
      unsigned u = pack2(hn, o);  // valid pair on even lanes
      if (tid >= 384 && tid < 416) {  // wave 6 lanes 0..31
        out[((size_t)t * 32 + b) * 256 + m * 32 + sl] = hn;
        if (t == len_b - 1) {
          hfin[b * 256 + m * 32 + sl] = hn;
          cfin[b * 256 + m * 32 + sl] = cn;
        }
        if (!(tid & 1)) {
          unsigned long long vv =
              ((unsigned long long)u << 32) | (unsigned long long)(unsigned)(t + 1);
          __hip_atomic_store(&hx[b * 128 + m * 16 + (sl >> 1)], vv, __ATOMIC_RELAXED,
                             __HIP_MEMORY_SCOPE_AGENT);
        }
      }
    }
    // no barrier at loop wrap: next P0 writes hcur/histF row t, whose prior
    // readers all finished before B2/B0 of this step; poll touches only global tags
  }
}

extern "C" void kernel_launch(void* const* d_in, const int* in_sizes, int n_in,
                              void* d_out, int out_size, void* d_ws, size_t ws_size,
                              hipStream_t stream) {
  const float* embs = (const float*)d_in[0];
  const int* lens = (const int*)d_in[1];
  const float* W_ih = (const float*)d_in[2];
  const float* W_hh = (const float*)d_in[3];
  const float* b_ih = (const float*)d_in[4];
  const float* b_hh = (const float*)d_in[5];
  const float* W_a = (const float*)d_in[6];
  const float* b_a = (const float*)d_in[7];

  float* out = (float*)d_out;                       // [T,B,H]
  float* hfin = out + (size_t)T_DIM * B_DIM * 256;  // [B,H]
  float* cfin = hfin + (size_t)B_DIM * 256;         // [B,H]

  char* ws = (char*)d_ws;
  float* gih = (float*)ws;
  float* W_ihT = (float*)(ws + 16777216);
  uint4* Whh_pack = (uint4*)(ws + 17825792);
  uint4* WaRow = (uint4*)(ws + 18350080);
  unsigned long long* hx = (unsigned long long*)(ws + 18612224);

  pack_weights<<<1024, 256, 0, stream>>>(W_ih, W_hh, W_a, W_ihT, Whh_pack, WaRow, hx);
  compute_gih<<<512, 256, 0, stream>>>(embs, W_ihT, b_ih, b_hh, gih);
  alstm_rec<<<256, 512, 0, stream>>>(lens, gih, Whh_pack, WaRow, b_a, hx, out, hfin, cfin);
}

// Round 7
// 537.351 us; speedup vs baseline: 1.1399x; 1.1399x over previous
//
#include <hip/hip_runtime.h>

// EncoderALSTM: T=128, B=32, H=256, I=256, 4H=1024.
// Round-14: re-anchor on the round-8 winner (439 us, passed) after 3 harness
// failures of the two-batch interleave (R11-R13, no timing data => setup-level
// failure; 4/4 single-batch kernels benched fine). Minimal serial-path cuts
// on top of byte-identical round-8 structure:
//   - gates: 4 independent fdot2 chains (was 2) -> dep chain 16->8
//   - score-publish dots: 4 chains (was 2) -> dep chain 16->4
//   - H' zp reduce: pairwise tree (depth 7->3)
// Protocol, layouts, barriers, launch config unchanged from round-8.
//
// ws layout (bytes):
//   gih      @0         16,777,216  fp32 [t*32+b][1024]
//   W_ihT    @16777216   1,048,576  fp32 (for compute_gih)
//   Whh_pack @17825792     524,288  uint4 [8 m][512 thr][8]
//   Wa_pack  @18350080     262,144  uint4 [8 m][256 j][8] (c<4: ctx cols, c>=4: h cols)
//   ywp      @18612224     524,288  u64 [32 b][8 m][256 j] tagged {y,w} partials
//   psx      @19136512     131,072  u64 [32 b][8 m][64]    tagged score-pair partials

#define T_DIM 128
#define B_DIM 32

typedef _Float16 half2_t __attribute__((ext_vector_type(2)));

static __device__ __forceinline__ unsigned pack2(float a, float b) {
  half2_t h;
  h.x = (_Float16)a;
  h.y = (_Float16)b;
  return __builtin_bit_cast(unsigned, h);
}

static __device__ __forceinline__ float dot2f(unsigned w, unsigned v, float acc) {
  half2_t a = __builtin_bit_cast(half2_t, w);
  half2_t b = __builtin_bit_cast(half2_t, v);
#if __has_builtin(__builtin_amdgcn_fdot2)
  return __builtin_amdgcn_fdot2(a, b, acc, false);
#else
  return acc + (float)a.x * (float)b.x + (float)a.y * (float)b.y;
#endif
}

static __device__ __forceinline__ float dot8(uint4 w, uint4 v, float acc) {
  acc = dot2f(w.x, v.x, acc);
  acc = dot2f(w.y, v.y, acc);
  acc = dot2f(w.z, v.z, acc);
  acc = dot2f(w.w, v.w, acc);
  return acc;
}

static __device__ __forceinline__ float lo16(unsigned u) {
  return (float)__builtin_bit_cast(half2_t, u).x;
}
static __device__ __forceinline__ float hi16(unsigned u) {
  return (float)__builtin_bit_cast(half2_t, u).y;
}

static __device__ __forceinline__ float fsig(float x) {
  return __builtin_amdgcn_rcpf(1.f + __expf(-x));
}
static __device__ __forceinline__ float ftanh(float x) {
  float e = __expf(2.f * x);
  return 1.f - 2.f * __builtin_amdgcn_rcpf(e + 1.f);
}

// ---------------- kernel 0: pack weights + zero tag buffers ----------------
__global__ void pack_weights(const float* __restrict__ W_ih, const float* __restrict__ W_hh,
                             const float* __restrict__ W_a, float* __restrict__ W_ihT,
                             uint4* __restrict__ Whh_pack, uint4* __restrict__ Wa_pack,
                             unsigned long long* __restrict__ ywp,
                             unsigned long long* __restrict__ psx) {
  int n = blockIdx.x * 256 + threadIdx.x;  // 0..262143
  {  // W_ihT[k][r] = W_ih[r][k]
    int k = n >> 10, r = n & 1023;
    W_ihT[n] = W_ih[r * 256 + k];
  }
  if (n < 32768) {  // Whh_pack[m][tid][i]: W_hh[r][(4i+qk)*8 ..+8]
    int m = n >> 12, tid = (n >> 3) & 511, i = n & 7;
    int r_local = tid >> 2, qk = tid & 3;
    int q = r_local >> 5, jl = r_local & 31;
    int r = q * 256 + m * 32 + jl;
    const float* src = W_hh + r * 256 + (4 * i + qk) * 8;
    uint4 v;
    v.x = pack2(src[0], src[1]);
    v.y = pack2(src[2], src[3]);
    v.z = pack2(src[4], src[5]);
    v.w = pack2(src[6], src[7]);
    Whh_pack[n] = v;
  }
  if (n < 16384) {  // Wa_pack[m][j][c]: c<4 -> ctx col m*32+c*8; c>=4 -> h col 256+m*32+(c-4)*8
    int m = n >> 11, j = (n >> 3) & 255, c = n & 7;
    int col0 = (c < 4) ? (m * 32 + c * 8) : (256 + m * 32 + (c - 4) * 8);
    const float* src = W_a + j * 512 + col0;
    uint4 v;
    v.x = pack2(src[0], src[1]);
    v.y = pack2(src[2], src[3]);
    v.z = pack2(src[4], src[5]);
    v.w = pack2(src[6], src[7]);
    Wa_pack[n] = v;
  }
  // zero tag buffers (atomic path, matches consumer)
  if (n < 65536)
    __hip_atomic_store(&ywp[n], 0ull, __ATOMIC_RELAXED, __HIP_MEMORY_SCOPE_AGENT);
  else if (n < 81920)
    __hip_atomic_store(&psx[n - 65536], 0ull, __ATOMIC_RELAXED, __HIP_MEMORY_SCOPE_AGENT);
}

// ---------------- kernel 1: gih = embs @ W_ih^T + b_ih + b_hh ----------------
__global__ void compute_gih(const float* __restrict__ embs, const float* __restrict__ W_ihT,
                            const float* __restrict__ b_ih, const float* __restrict__ b_hh,
                            float* __restrict__ gih) {
  __shared__ float embS[8][256];
  const int tid = threadIdx.x;     // 256 threads
  const int tb0 = blockIdx.x * 8;  // 512 blocks x 8 (t,b) pairs
#pragma unroll
  for (int e = 0; e < 8; ++e) embS[e][tid] = embs[(size_t)(tb0 + e) * 256 + tid];
  __syncthreads();
  float acc[8][4];
#pragma unroll
  for (int e = 0; e < 8; ++e)
#pragma unroll
    for (int q = 0; q < 4; ++q) acc[e][q] = 0.f;
  for (int k = 0; k < 256; ++k) {
    float w0 = W_ihT[k * 1024 + tid];
    float w1 = W_ihT[k * 1024 + tid + 256];
    float w2 = W_ihT[k * 1024 + tid + 512];
    float w3 = W_ihT[k * 1024 + tid + 768];
#pragma unroll
    for (int e = 0; e < 8; ++e) {
      float x = embS[e][k];
      acc[e][0] += x * w0;
      acc[e][1] += x * w1;
      acc[e][2] += x * w2;
      acc[e][3] += x * w3;
    }
  }
#pragma unroll
  for (int q = 0; q < 4; ++q) {
    float bias = b_ih[q * 256 + tid] + b_hh[q * 256 + tid];
#pragma unroll
    for (int e = 0; e < 8; ++e)
      gih[(size_t)(tb0 + e) * 1024 + q * 256 + tid] = acc[e][q] + bias;
  }
}

// ---------------- kernel 2: recurrent, distributed scores ----------------
__global__ void __launch_bounds__(512, 1)
alstm_rec(const int* __restrict__ lens, const float* __restrict__ gih,
          const uint4* __restrict__ Whh_pack, const uint4* __restrict__ Wa_pack,
          const float* __restrict__ b_a, unsigned long long* __restrict__ ywp,
          unsigned long long* __restrict__ psx, float* __restrict__ out,
          float* __restrict__ hfin, float* __restrict__ cfin) {
  const int tid = threadIdx.x;  // 512 threads
  const int b = blockIdx.x & 31;
  const int m = blockIdx.x >> 5;

  __shared__ __align__(16) unsigned histSl[128 * 18];  // own h slice history, 9 KB (stride 18)
  __shared__ __align__(16) float ystoreF[128 * 256];   // y history f32, 128 KB
  __shared__ __align__(16) unsigned hp2[128];          // h' pairs
  __shared__ __align__(16) float sc[128];              // normalized alpha
  __shared__ __align__(16) float zp[8][256];           // z partials (8 s-phases)
  __shared__ float gsl[128];

  // ---- register-resident weights ----
  uint4 wh4[8];
  {
    const uint4* p = Whh_pack + ((size_t)m * 512 + tid) * 8;
#pragma unroll
    for (int i = 0; i < 8; ++i) wh4[i] = p[i];
  }
  uint4 way[4], waw[4];  // W_a slice cols for publish row j_pub
  {
    const int j_pub = (tid - 128) & 255;
    const uint4* p = Wa_pack + ((size_t)m * 256 + j_pub) * 8;
#pragma unroll
    for (int i = 0; i < 4; ++i) way[i] = p[i];
#pragma unroll
    for (int i = 0; i < 4; ++i) waw[i] = p[4 + i];
  }
  const float ba_j = (tid < 256) ? b_a[tid] : 0.f;
  const int len_b = lens[b];
  const int r_local = tid >> 2, qk = tid & 3;
  const int gq = r_local >> 5, gjl = r_local & 31;

  if (tid < 128) hp2[tid] = 0u;
  float c_reg = 0.f;  // replicated per-lane (sl = tid&31), consistent across waves
  __syncthreads();

  for (int t = 0; t < T_DIM; ++t) {
    float gih_v = gih[((size_t)t * 32 + b) * 1024 + gq * 256 + m * 32 + gjl];
    float w_j = 0.f;

    if (t > 0) {
      // ---- ONE poll point: yw partials (tid<256) || score partials + fused softmax (wave 4) ----
      if (tid < 256) {
        const unsigned long long* base = ywp + b * 2048 + tid;
        unsigned long long v[8];
        for (;;) {
          bool ok = true;
#pragma unroll
          for (int mm = 0; mm < 8; ++mm)
            v[mm] = __hip_atomic_load(base + mm * 256, __ATOMIC_RELAXED, __HIP_MEMORY_SCOPE_AGENT);
#pragma unroll
          for (int mm = 0; mm < 8; ++mm) ok &= ((unsigned)v[mm] == (unsigned)t);
          if (ok) break;
          __builtin_amdgcn_s_sleep(1);
        }
        float y = 0.f, w = 0.f;
#pragma unroll
        for (int mm = 0; mm < 8; ++mm) {
          unsigned pl = (unsigned)(v[mm] >> 32);
          y += lo16(pl);
          w += hi16(pl);
        }
        w_j = w;
        ystoreF[(t - 1) * 256 + tid] = y;
      } else if (tid < 320) {
        const int p = tid - 256;  // score pair index; wave 4 holds all 128 scores
        const unsigned long long* base = psx + b * 512 + p;
        unsigned long long v[8];
        for (;;) {
          bool ok = true;
#pragma unroll
          for (int mm = 0; mm < 8; ++mm)
            v[mm] = __hip_atomic_load(base + mm * 64, __ATOMIC_RELAXED, __HIP_MEMORY_SCOPE_AGENT);
#pragma unroll
          for (int mm = 0; mm < 8; ++mm) ok &= ((unsigned)v[mm] == (unsigned)t);
          if (ok) break;
          __builtin_amdgcn_s_sleep(1);
        }
        float s0 = 0.f, s1 = 0.f;
#pragma unroll
        for (int mm = 0; mm < 8; ++mm) {
          unsigned pl = (unsigned)(v[mm] >> 32);
          s0 += lo16(pl);
          s1 += hi16(pl);
        }
        // fused softmax over s in [0,t), entirely within wave 4
        float v0 = (2 * p < t) ? s0 : -3.0e38f;
        float v1 = (2 * p + 1 < t) ? s1 : -3.0e38f;
        float mx = fmaxf(v0, v1);
#pragma unroll
        for (int off = 32; off >= 1; off >>= 1) mx = fmaxf(mx, __shfl_xor(mx, off));
        float e0 = (2 * p < t) ? __expf(v0 - mx) : 0.f;
        float e1 = (2 * p + 1 < t) ? __expf(v1 - mx) : 0.f;
        float sm = e0 + e1;
#pragma unroll
        for (int off = 32; off >= 1; off >>= 1) sm += __shfl_xor(sm, off);
        float inv = __builtin_amdgcn_rcpf(sm);
        sc[2 * p] = e0 * inv;
        sc[2 * p + 1] = e1 * inv;
      }
      __syncthreads();  // B1: alpha + ystoreF[t-1] ready
      // ---- Z: 8 s-phases x float4 over f32 y-history ----
      {
        const int sp = tid >> 6, cg = tid & 63;
        float c0 = 0.f, c1 = 0.f, c2 = 0.f, c3 = 0.f;
        const float* yb = ystoreF + 4 * cg;
        for (int s = sp; s < t; s += 8) {
          float al = sc[s];
          const float4 yv = *(const float4*)(yb + (size_t)s * 256);
          c0 += al * yv.x;
          c1 += al * yv.y;
          c2 += al * yv.z;
          c3 += al * yv.w;
        }
        float4 st;
        st.x = c0;
        st.y = c1;
        st.z = c2;
        st.w = c3;
        *(float4*)&zp[sp][4 * cg] = st;
      }
      __syncthreads();  // B2: zp ready
      // ---- H': h'_j = tanh(ba + w + z), pairwise-tree zp reduce ----
      if (tid < 256) {
        float z01 = zp[0][tid] + zp[1][tid];
        float z23 = zp[2][tid] + zp[3][tid];
        float z45 = zp[4][tid] + zp[5][tid];
        float z67 = zp[6][tid] + zp[7][tid];
        float z = (z01 + z23) + (z45 + z67);
        float hv = ftanh(ba_j + w_j + z);
        float o = __shfl_xor(hv, 1);
        if (!(tid & 1)) hp2[tid >> 1] = pack2(hv, o);
      }
      __syncthreads();  // B3: hp2 ready
    }
    // ---- F: gates row r_local, chunks c==qk (mod 4); 4 independent chains ----
    {
      float a0 = 0.f, a1 = 0.f, a2 = 0.f, a3 = 0.f;
#pragma unroll
      for (int i = 0; i < 8; i += 4) {
        uint4 hv0 = *(const uint4*)&hp2[(4 * i + qk) << 2];
        uint4 hv1 = *(const uint4*)&hp2[(4 * (i + 1) + qk) << 2];
        uint4 hv2 = *(const uint4*)&hp2[(4 * (i + 2) + qk) << 2];
        uint4 hv3 = *(const uint4*)&hp2[(4 * (i + 3) + qk) << 2];
        a0 = dot8(wh4[i], hv0, a0);
        a1 = dot8(wh4[i + 1], hv1, a1);
        a2 = dot8(wh4[i + 2], hv2, a2);
        a3 = dot8(wh4[i + 3], hv3, a3);
      }
      float a = (a0 + a1) + (a2 + a3);
      a += __shfl_xor(a, 1);
      a += __shfl_xor(a, 2);
      if (qk == 0) gsl[r_local] = a + gih_v;
    }
    __syncthreads();  // B4: gsl ready
    // ---- cell: redundant in EVERY wave (deterministic replicas); no barrier after ----
    unsigned hq[16];
    {
      const int sl = tid & 31;
      float ig = fsig(gsl[sl]);
      float fg = fsig(gsl[32 + sl]);
      float gg = ftanh(gsl[64 + sl]);
      float og = fsig(gsl[96 + sl]);
      float cn = fg * c_reg + ig * gg;
      float hn = og * ftanh(cn);
      c_reg = cn;
      if (tid >= 384 && tid < 416) {  // wave 6: global stores + history write
        out[((size_t)t * 32 + b) * 256 + m * 32 + sl] = hn;
        if (t == len_b - 1) {
          hfin[b * 256 + m * 32 + sl] = hn;
          cfin[b * 256 + m * 32 + sl] = cn;
        }
      }
      float o = __shfl_xor(hn, 1);
      unsigned u = pack2(hn, o);  // valid pair on even lanes
      if (tid >= 384 && tid < 416 && !(tid & 1)) histSl[t * 18 + (sl >> 1)] = u;
      // in-wave broadcast of all 16 slice pairs
#pragma unroll
      for (int k = 0; k < 16; ++k) hq[k] = __shfl(u, 2 * k);
    }
    // ---- publish: score partials (waves 0-1) + y/w partials (waves 2-5) ----
    if (tid < 128) {
      float a0 = 0.f, a1 = 0.f, a2 = 0.f, a3 = 0.f;
      if (tid == t) {
        // entry s==t is this step's own h: use wave-private regs (histSl[t] is
        // being written concurrently by wave 6)
#pragma unroll
        for (int k = 0; k < 8; k += 4) {
          a0 = dot2f(hq[2 * k], hq[2 * k], a0);
          a0 = dot2f(hq[2 * k + 1], hq[2 * k + 1], a0);
          a1 = dot2f(hq[2 * k + 2], hq[2 * k + 2], a1);
          a1 = dot2f(hq[2 * k + 3], hq[2 * k + 3], a1);
          a2 = dot2f(hq[2 * k + 4], hq[2 * k + 4], a2);
          a2 = dot2f(hq[2 * k + 5], hq[2 * k + 5], a2);
          a3 = dot2f(hq[2 * k + 6], hq[2 * k + 6], a3);
          a3 = dot2f(hq[2 * k + 7], hq[2 * k + 7], a3);
        }
      } else {
#pragma unroll
        for (int k = 0; k < 8; k += 4) {
          uint2 hw0 = *(const uint2*)&histSl[tid * 18 + 2 * k];
          uint2 hw1 = *(const uint2*)&histSl[tid * 18 + 2 * k + 2];
          uint2 hw2 = *(const uint2*)&histSl[tid * 18 + 2 * k + 4];
          uint2 hw3 = *(const uint2*)&histSl[tid * 18 + 2 * k + 6];
          a0 = dot2f(hw0.x, hq[2 * k], a0);
          a0 = dot2f(hw0.y, hq[2 * k + 1], a0);
          a1 = dot2f(hw1.x, hq[2 * k + 2], a1);
          a1 = dot2f(hw1.y, hq[2 * k + 3], a1);
          a2 = dot2f(hw2.x, hq[2 * k + 4], a2);
          a2 = dot2f(hw2.y, hq[2 * k + 5], a2);
          a3 = dot2f(hw3.x, hq[2 * k + 6], a3);
          a3 = dot2f(hw3.y, hq[2 * k + 7], a3);
        }
      }
      float a = (a0 + a1) + (a2 + a3);
      float o = __shfl_xor(a, 1);
      if (!(tid & 1)) {
        unsigned long long vv = ((unsigned long long)pack2(a, o) << 32) |
                                (unsigned long long)(unsigned)(t + 1);
        __hip_atomic_store(&psx[b * 512 + m * 64 + (tid >> 1)], vv, __ATOMIC_RELAXED,
                           __HIP_MEMORY_SCOPE_AGENT);
      }
    } else if (tid < 384) {
      const int j = tid - 128;
      uint4 hv0 = make_uint4(hq[0], hq[1], hq[2], hq[3]);
      uint4 hv1 = make_uint4(hq[4], hq[5], hq[6], hq[7]);
      uint4 hv2 = make_uint4(hq[8], hq[9], hq[10], hq[11]);
      uint4 hv3 = make_uint4(hq[12], hq[13], hq[14], hq[15]);
      float ay0 = 0.f, ay1 = 0.f, aw0 = 0.f, aw1 = 0.f;
      ay0 = dot8(way[0], hv0, ay0);
      aw0 = dot8(waw[0], hv0, aw0);
      ay1 = dot8(way[1], hv1, ay1);
      aw1 = dot8(waw[1], hv1, aw1);
      ay0 = dot8(way[2], hv2, ay0);
      aw0 = dot8(waw[2], hv2, aw0);
      ay1 = dot8(way[3], hv3, ay1);
      aw1 = dot8(waw[3], hv3, aw1);
      unsigned long long vv = ((unsigned long long)pack2(ay0 + ay1, aw0 + aw1) << 32) |
                              (unsigned long long)(unsigned)(t + 1);
      __hip_atomic_store(&ywp[b * 2048 + m * 256 + j], vv, __ATOMIC_RELAXED,
                         __HIP_MEMORY_SCOPE_AGENT);
    }
    // no barrier at loop wrap: next poll touches only global tags; all LDS
    // cross-phase hazards are separated by B1..B4 of the next iteration
  }
}

extern "C" void kernel_launch(void* const* d_in, const int* in_sizes, int n_in,
                              void* d_out, int out_size, void* d_ws, size_t ws_size,
                              hipStream_t stream) {
  const float* embs = (const float*)d_in[0];
  const int* lens = (const int*)d_in[1];
  const float* W_ih = (const float*)d_in[2];
  const float* W_hh = (const float*)d_in[3];
  const float* b_ih = (const float*)d_in[4];
  const float* b_hh = (const float*)d_in[5];
  const float* W_a = (const float*)d_in[6];
  const float* b_a = (const float*)d_in[7];

  float* out = (float*)d_out;                       // [T,B,H]
  float* hfin = out + (size_t)T_DIM * B_DIM * 256;  // [B,H]
  float* cfin = hfin + (size_t)B_DIM * 256;         // [B,H]

  char* ws = (char*)d_ws;
  float* gih = (float*)ws;
  float* W_ihT = (float*)(ws + 16777216);
  uint4* Whh_pack = (uint4*)(ws + 17825792);
  uint4* Wa_pack = (uint4*)(ws + 18350080);
  unsigned long long* ywp = (unsigned long long*)(ws + 18612224);
  unsigned long long* psx = (unsigned long long*)(ws + 19136512);

  pack_weights<<<1024, 256, 0, stream>>>(W_ih, W_hh, W_a, W_ihT, Whh_pack, Wa_pack, ywp, psx);
  compute_gih<<<512, 256, 0, stream>>>(embs, W_ihT, b_ih, b_hh, gih);
  alstm_rec<<<256, 512, 0, stream>>>(lens, gih, Whh_pack, Wa_pack, b_a, ywp, psx, out, hfin,
                                     cfin);
}

// Round 9
// 535.890 us; speedup vs baseline: 1.1430x; 1.0027x over previous
//
#include <hip/hip_runtime.h>

// EncoderALSTM: T=128, B=32, H=256, I=256, 4H=1024.
// Round-16: R14 anchor (440 us, passed) + poll micro-latency cuts.
// History: two-batch interleave abandoned after 4/4 HW failures (R15's bounded
// spin proved tags never arrive: absmax 0.266, ~220 s pytest = every poll
// capping). Proven-null levers: comm volume (R10), fan-in (R9), ALU chain
// depth (R14); extra VALU costs ~1:1 (R10). Remaining modeled costs: poll
// detection quantization (s_sleep 64-cyc quantum + one 8-load/vmcnt re-check
// iteration after arrival) and possible DVFS downclock from sleep-heavy
// waves. This round: drop s_sleep from both poll loops (busy-spin) — no
// forward-progress hazard (producers live on other CUs; publish precedes
// poll in program order).
//
// ws layout (bytes):
//   gih      @0         16,777,216  fp32 [t*32+b][1024]
//   W_ihT    @16777216   1,048,576  fp32 (for compute_gih)
//   Whh_pack @17825792     524,288  uint4 [8 m][512 thr][8]
//   Wa_pack  @18350080     262,144  uint4 [8 m][256 j][8] (c<4: ctx cols, c>=4: h cols)
//   ywp      @18612224     524,288  u64 [32 b][8 m][256 j] tagged {y,w} partials
//   psx      @19136512     131,072  u64 [32 b][8 m][64]    tagged score-pair partials

#define T_DIM 128
#define B_DIM 32

typedef _Float16 half2_t __attribute__((ext_vector_type(2)));

static __device__ __forceinline__ unsigned pack2(float a, float b) {
  half2_t h;
  h.x = (_Float16)a;
  h.y = (_Float16)b;
  return __builtin_bit_cast(unsigned, h);
}

static __device__ __forceinline__ float dot2f(unsigned w, unsigned v, float acc) {
  half2_t a = __builtin_bit_cast(half2_t, w);
  half2_t b = __builtin_bit_cast(half2_t, v);
#if __has_builtin(__builtin_amdgcn_fdot2)
  return __builtin_amdgcn_fdot2(a, b, acc, false);
#else
  return acc + (float)a.x * (float)b.x + (float)a.y * (float)b.y;
#endif
}

static __device__ __forceinline__ float dot8(uint4 w, uint4 v, float acc) {
  acc = dot2f(w.x, v.x, acc);
  acc = dot2f(w.y, v.y, acc);
  acc = dot2f(w.z, v.z, acc);
  acc = dot2f(w.w, v.w, acc);
  return acc;
}

static __device__ __forceinline__ float lo16(unsigned u) {
  return (float)__builtin_bit_cast(half2_t, u).x;
}
static __device__ __forceinline__ float hi16(unsigned u) {
  return (float)__builtin_bit_cast(half2_t, u).y;
}

static __device__ __forceinline__ float fsig(float x) {
  return __builtin_amdgcn_rcpf(1.f + __expf(-x));
}
static __device__ __forceinline__ float ftanh(float x) {
  float e = __expf(2.f * x);
  return 1.f - 2.f * __builtin_amdgcn_rcpf(e + 1.f);
}

// ---------------- kernel 0: pack weights + zero tag buffers ----------------
__global__ void pack_weights(const float* __restrict__ W_ih, const float* __restrict__ W_hh,
                             const float* __restrict__ W_a, float* __restrict__ W_ihT,
                             uint4* __restrict__ Whh_pack, uint4* __restrict__ Wa_pack,
                             unsigned long long* __restrict__ ywp,
                             unsigned long long* __restrict__ psx) {
  int n = blockIdx.x * 256 + threadIdx.x;  // 0..262143
  {  // W_ihT[k][r] = W_ih[r][k]
    int k = n >> 10, r = n & 1023;
    W_ihT[n] = W_ih[r * 256 + k];
  }
  if (n < 32768) {  // Whh_pack[m][tid][i]: W_hh[r][(4i+qk)*8 ..+8]
    int m = n >> 12, tid = (n >> 3) & 511, i = n & 7;
    int r_local = tid >> 2, qk = tid & 3;
    int q = r_local >> 5, jl = r_local & 31;
    int r = q * 256 + m * 32 + jl;
    const float* src = W_hh + r * 256 + (4 * i + qk) * 8;
    uint4 v;
    v.x = pack2(src[0], src[1]);
    v.y = pack2(src[2], src[3]);
    v.z = pack2(src[4], src[5]);
    v.w = pack2(src[6], src[7]);
    Whh_pack[n] = v;
  }
  if (n < 16384) {  // Wa_pack[m][j][c]: c<4 -> ctx col m*32+c*8; c>=4 -> h col 256+m*32+(c-4)*8
    int m = n >> 11, j = (n >> 3) & 255, c = n & 7;
    int col0 = (c < 4) ? (m * 32 + c * 8) : (256 + m * 32 + (c - 4) * 8);
    const float* src = W_a + j * 512 + col0;
    uint4 v;
    v.x = pack2(src[0], src[1]);
    v.y = pack2(src[2], src[3]);
    v.z = pack2(src[4], src[5]);
    v.w = pack2(src[6], src[7]);
    Wa_pack[n] = v;
  }
  // zero tag buffers (atomic path, matches consumer)
  if (n < 65536)
    __hip_atomic_store(&ywp[n], 0ull, __ATOMIC_RELAXED, __HIP_MEMORY_SCOPE_AGENT);
  else if (n < 81920)
    __hip_atomic_store(&psx[n - 65536], 0ull, __ATOMIC_RELAXED, __HIP_MEMORY_SCOPE_AGENT);
}

// ---------------- kernel 1: gih = embs @ W_ih^T + b_ih + b_hh ----------------
__global__ void compute_gih(const float* __restrict__ embs, const float* __restrict__ W_ihT,
                            const float* __restrict__ b_ih, const float* __restrict__ b_hh,
                            float* __restrict__ gih) {
  __shared__ float embS[8][256];
  const int tid = threadIdx.x;     // 256 threads
  const int tb0 = blockIdx.x * 8;  // 512 blocks x 8 (t,b) pairs
#pragma unroll
  for (int e = 0; e < 8; ++e) embS[e][tid] = embs[(size_t)(tb0 + e) * 256 + tid];
  __syncthreads();
  float acc[8][4];
#pragma unroll
  for (int e = 0; e < 8; ++e)
#pragma unroll
    for (int q = 0; q < 4; ++q) acc[e][q] = 0.f;
  for (int k = 0; k < 256; ++k) {
    float w0 = W_ihT[k * 1024 + tid];
    float w1 = W_ihT[k * 1024 + tid + 256];
    float w2 = W_ihT[k * 1024 + tid + 512];
    float w3 = W_ihT[k * 1024 + tid + 768];
#pragma unroll
    for (int e = 0; e < 8; ++e) {
      float x = embS[e][k];
      acc[e][0] += x * w0;
      acc[e][1] += x * w1;
      acc[e][2] += x * w2;
      acc[e][3] += x * w3;
    }
  }
#pragma unroll
  for (int q = 0; q < 4; ++q) {
    float bias = b_ih[q * 256 + tid] + b_hh[q * 256 + tid];
#pragma unroll
    for (int e = 0; e < 8; ++e)
      gih[(size_t)(tb0 + e) * 1024 + q * 256 + tid] = acc[e][q] + bias;
  }
}

// ---------------- kernel 2: recurrent, distributed scores ----------------
__global__ void __launch_bounds__(512, 1)
alstm_rec(const int* __restrict__ lens, const float* __restrict__ gih,
          const uint4* __restrict__ Whh_pack, const uint4* __restrict__ Wa_pack,
          const float* __restrict__ b_a, unsigned long long* __restrict__ ywp,
          unsigned long long* __restrict__ psx, float* __restrict__ out,
          float* __restrict__ hfin, float* __restrict__ cfin) {
  const int tid = threadIdx.x;  // 512 threads
  const int b = blockIdx.x & 31;
  const int m = blockIdx.x >> 5;

  __shared__ __align__(16) unsigned histSl[128 * 18];  // own h slice history, 9 KB (stride 18)
  __shared__ __align__(16) float ystoreF[128 * 256];   // y history f32, 128 KB
  __shared__ __align__(16) unsigned hp2[128];          // h' pairs
  __shared__ __align__(16) float sc[128];              // normalized alpha
  __shared__ __align__(16) float zp[8][256];           // z partials (8 s-phases)
  __shared__ float gsl[128];

  // ---- register-resident weights ----
  uint4 wh4[8];
  {
    const uint4* p = Whh_pack + ((size_t)m * 512 + tid) * 8;
#pragma unroll
    for (int i = 0; i < 8; ++i) wh4[i] = p[i];
  }
  uint4 way[4], waw[4];  // W_a slice cols for publish row j_pub
  {
    const int j_pub = (tid - 128) & 255;
    const uint4* p = Wa_pack + ((size_t)m * 256 + j_pub) * 8;
#pragma unroll
    for (int i = 0; i < 4; ++i) way[i] = p[i];
#pragma unroll
    for (int i = 0; i < 4; ++i) waw[i] = p[4 + i];
  }
  const float ba_j = (tid < 256) ? b_a[tid] : 0.f;
  const int len_b = lens[b];
  const int r_local = tid >> 2, qk = tid & 3;
  const int gq = r_local >> 5, gjl = r_local & 31;

  if (tid < 128) hp2[tid] = 0u;
  float c_reg = 0.f;  // replicated per-lane (sl = tid&31), consistent across waves
  __syncthreads();

  for (int t = 0; t < T_DIM; ++t) {
    float gih_v = gih[((size_t)t * 32 + b) * 1024 + gq * 256 + m * 32 + gjl];
    float w_j = 0.f;

    if (t > 0) {
      // ---- ONE poll point: yw partials (tid<256) || score partials + fused softmax (wave 4) ----
      // busy-spin, no s_sleep: removes the 64-cyc detection quantum and keeps
      // the CU issue pipes active (DVFS governor hint). Producers are on other
      // CUs; our own publish precedes this poll in program order -> no hazard.
      if (tid < 256) {
        const unsigned long long* base = ywp + b * 2048 + tid;
        unsigned long long v[8];
        for (;;) {
          bool ok = true;
#pragma unroll
          for (int mm = 0; mm < 8; ++mm)
            v[mm] = __hip_atomic_load(base + mm * 256, __ATOMIC_RELAXED, __HIP_MEMORY_SCOPE_AGENT);
#pragma unroll
          for (int mm = 0; mm < 8; ++mm) ok &= ((unsigned)v[mm] == (unsigned)t);
          if (ok) break;
        }
        float y = 0.f, w = 0.f;
#pragma unroll
        for (int mm = 0; mm < 8; ++mm) {
          unsigned pl = (unsigned)(v[mm] >> 32);
          y += lo16(pl);
          w += hi16(pl);
        }
        w_j = w;
        ystoreF[(t - 1) * 256 + tid] = y;
      } else if (tid < 320) {
        const int p = tid - 256;  // score pair index; wave 4 holds all 128 scores
        const unsigned long long* base = psx + b * 512 + p;
        unsigned long long v[8];
        for (;;) {
          bool ok = true;
#pragma unroll
          for (int mm = 0; mm < 8; ++mm)
            v[mm] = __hip_atomic_load(base + mm * 64, __ATOMIC_RELAXED, __HIP_MEMORY_SCOPE_AGENT);
#pragma unroll
          for (int mm = 0; mm < 8; ++mm) ok &= ((unsigned)v[mm] == (unsigned)t);
          if (ok) break;
        }
        float s0 = 0.f, s1 = 0.f;
#pragma unroll
        for (int mm = 0; mm < 8; ++mm) {
          unsigned pl = (unsigned)(v[mm] >> 32);
          s0 += lo16(pl);
          s1 += hi16(pl);
        }
        // fused softmax over s in [0,t), entirely within wave 4
        float v0 = (2 * p < t) ? s0 : -3.0e38f;
        float v1 = (2 * p + 1 < t) ? s1 : -3.0e38f;
        float mx = fmaxf(v0, v1);
#pragma unroll
        for (int off = 32; off >= 1; off >>= 1) mx = fmaxf(mx, __shfl_xor(mx, off));
        float e0 = (2 * p < t) ? __expf(v0 - mx) : 0.f;
        float e1 = (2 * p + 1 < t) ? __expf(v1 - mx) : 0.f;
        float sm = e0 + e1;
#pragma unroll
        for (int off = 32; off >= 1; off >>= 1) sm += __shfl_xor(sm, off);
        float inv = __builtin_amdgcn_rcpf(sm);
        sc[2 * p] = e0 * inv;
        sc[2 * p + 1] = e1 * inv;
      }
      __syncthreads();  // B1: alpha + ystoreF[t-1] ready
      // ---- Z: 8 s-phases x float4 over f32 y-history ----
      {
        const int sp = tid >> 6, cg = tid & 63;
        float c0 = 0.f, c1 = 0.f, c2 = 0.f, c3 = 0.f;
        const float* yb = ystoreF + 4 * cg;
        for (int s = sp; s < t; s += 8) {
          float al = sc[s];
          const float4 yv = *(const float4*)(yb + (size_t)s * 256);
          c0 += al * yv.x;
          c1 += al * yv.y;
          c2 += al * yv.z;
          c3 += al * yv.w;
        }
        float4 st;
        st.x = c0;
        st.y = c1;
        st.z = c2;
        st.w = c3;
        *(float4*)&zp[sp][4 * cg] = st;
      }
      __syncthreads();  // B2: zp ready
      // ---- H': h'_j = tanh(ba + w + z), pairwise-tree zp reduce ----
      if (tid < 256) {
        float z01 = zp[0][tid] + zp[1][tid];
        float z23 = zp[2][tid] + zp[3][tid];
        float z45 = zp[4][tid] + zp[5][tid];
        float z67 = zp[6][tid] + zp[7][tid];
        float z = (z01 + z23) + (z45 + z67);
        float hv = ftanh(ba_j + w_j + z);
        float o = __shfl_xor(hv, 1);
        if (!(tid & 1)) hp2[tid >> 1] = pack2(hv, o);
      }
      __syncthreads();  // B3: hp2 ready
    }
    // ---- F: gates row r_local, chunks c==qk (mod 4); 4 independent chains ----
    {
      float a0 = 0.f, a1 = 0.f, a2 = 0.f, a3 = 0.f;
#pragma unroll
      for (int i = 0; i < 8; i += 4) {
        uint4 hv0 = *(const uint4*)&hp2[(4 * i + qk) << 2];
        uint4 hv1 = *(const uint4*)&hp2[(4 * (i + 1) + qk) << 2];
        uint4 hv2 = *(const uint4*)&hp2[(4 * (i + 2) + qk) << 2];
        uint4 hv3 = *(const uint4*)&hp2[(4 * (i + 3) + qk) << 2];
        a0 = dot8(wh4[i], hv0, a0);
        a1 = dot8(wh4[i + 1], hv1, a1);
        a2 = dot8(wh4[i + 2], hv2, a2);
        a3 = dot8(wh4[i + 3], hv3, a3);
      }
      float a = (a0 + a1) + (a2 + a3);
      a += __shfl_xor(a, 1);
      a += __shfl_xor(a, 2);
      if (qk == 0) gsl[r_local] = a + gih_v;
    }
    __syncthreads();  // B4: gsl ready
    // ---- cell: redundant in EVERY wave (deterministic replicas); no barrier after ----
    unsigned hq[16];
    {
      const int sl = tid & 31;
      float ig = fsig(gsl[sl]);
      float fg = fsig(gsl[32 + sl]);
      float gg = ftanh(gsl[64 + sl]);
      float og = fsig(gsl[96 + sl]);
      float cn = fg * c_reg + ig * gg;
      float hn = og * ftanh(cn);
      c_reg = cn;
      if (tid >= 384 && tid < 416) {  // wave 6: global stores + history write
        out[((size_t)t * 32 + b) * 256 + m * 32 + sl] = hn;
        if (t == len_b - 1) {
          hfin[b * 256 + m * 32 + sl] = hn;
          cfin[b * 256 + m * 32 + sl] = cn;
        }
      }
      float o = __shfl_xor(hn, 1);
      unsigned u = pack2(hn, o);  // valid pair on even lanes
      if (tid >= 384 && tid < 416 && !(tid & 1)) histSl[t * 18 + (sl >> 1)] = u;
      // in-wave broadcast of all 16 slice pairs
#pragma unroll
      for (int k = 0; k < 16; ++k) hq[k] = __shfl(u, 2 * k);
    }
    // ---- publish: score partials (waves 0-1) + y/w partials (waves 2-5) ----
    if (tid < 128) {
      float a0 = 0.f, a1 = 0.f, a2 = 0.f, a3 = 0.f;
      if (tid == t) {
        // entry s==t is this step's own h: use wave-private regs (histSl[t] is
        // being written concurrently by wave 6)
#pragma unroll
        for (int k = 0; k < 8; k += 4) {
          a0 = dot2f(hq[2 * k], hq[2 * k], a0);
          a0 = dot2f(hq[2 * k + 1], hq[2 * k + 1], a0);
          a1 = dot2f(hq[2 * k + 2], hq[2 * k + 2], a1);
          a1 = dot2f(hq[2 * k + 3], hq[2 * k + 3], a1);
          a2 = dot2f(hq[2 * k + 4], hq[2 * k + 4], a2);
          a2 = dot2f(hq[2 * k + 5], hq[2 * k + 5], a2);
          a3 = dot2f(hq[2 * k + 6], hq[2 * k + 6], a3);
          a3 = dot2f(hq[2 * k + 7], hq[2 * k + 7], a3);
        }
      } else {
#pragma unroll
        for (int k = 0; k < 8; k += 4) {
          uint2 hw0 = *(const uint2*)&histSl[tid * 18 + 2 * k];
          uint2 hw1 = *(const uint2*)&histSl[tid * 18 + 2 * k + 2];
          uint2 hw2 = *(const uint2*)&histSl[tid * 18 + 2 * k + 4];
          uint2 hw3 = *(const uint2*)&histSl[tid * 18 + 2 * k + 6];
          a0 = dot2f(hw0.x, hq[2 * k], a0);
          a0 = dot2f(hw0.y, hq[2 * k + 1], a0);
          a1 = dot2f(hw1.x, hq[2 * k + 2], a1);
          a1 = dot2f(hw1.y, hq[2 * k + 3], a1);
          a2 = dot2f(hw2.x, hq[2 * k + 4], a2);
          a2 = dot2f(hw2.y, hq[2 * k + 5], a2);
          a3 = dot2f(hw3.x, hq[2 * k + 6], a3);
          a3 = dot2f(hw3.y, hq[2 * k + 7], a3);
        }
      }
      float a = (a0 + a1) + (a2 + a3);
      float o = __shfl_xor(a, 1);
      if (!(tid & 1)) {
        unsigned long long vv = ((unsigned long long)pack2(a, o) << 32) |
                                (unsigned long long)(unsigned)(t + 1);
        __hip_atomic_store(&psx[b * 512 + m * 64 + (tid >> 1)], vv, __ATOMIC_RELAXED,
                           __HIP_MEMORY_SCOPE_AGENT);
      }
    } else if (tid < 384) {
      const int j = tid - 128;
      uint4 hv0 = make_uint4(hq[0], hq[1], hq[2], hq[3]);
      uint4 hv1 = make_uint4(hq[4], hq[5], hq[6], hq[7]);
      uint4 hv2 = make_uint4(hq[8], hq[9], hq[10], hq[11]);
      uint4 hv3 = make_uint4(hq[12], hq[13], hq[14], hq[15]);
      float ay0 = 0.f, ay1 = 0.f, aw0 = 0.f, aw1 = 0.f;
      ay0 = dot8(way[0], hv0, ay0);
      aw0 = dot8(waw[0], hv0, aw0);
      ay1 = dot8(way[1], hv1, ay1);
      aw1 = dot8(waw[1], hv1, aw1);
      ay0 = dot8(way[2], hv2, ay0);
      aw0 = dot8(waw[2], hv2, aw0);
      ay1 = dot8(way[3], hv3, ay1);
      aw1 = dot8(waw[3], hv3, aw1);
      unsigned long long vv = ((unsigned long long)pack2(ay0 + ay1, aw0 + aw1) << 32) |
                              (unsigned long long)(unsigned)(t + 1);
      __hip_atomic_store(&ywp[b * 2048 + m * 256 + j], vv, __ATOMIC_RELAXED,
                         __HIP_MEMORY_SCOPE_AGENT);
    }
    // no barrier at loop wrap: next poll touches only global tags; all LDS
    // cross-phase hazards are separated by B1..B4 of the next iteration
  }
}

extern "C" void kernel_launch(void* const* d_in, const int* in_sizes, int n_in,
                              void* d_out, int out_size, void* d_ws, size_t ws_size,
                              hipStream_t stream) {
  const float* embs = (const float*)d_in[0];
  const int* lens = (const int*)d_in[1];
  const float* W_ih = (const float*)d_in[2];
  const float* W_hh = (const float*)d_in[3];
  const float* b_ih = (const float*)d_in[4];
  const float* b_hh = (const float*)d_in[5];
  const float* W_a = (const float*)d_in[6];
  const float* b_a = (const float*)d_in[7];

  float* out = (float*)d_out;                       // [T,B,H]
  float* hfin = out + (size_t)T_DIM * B_DIM * 256;  // [B,H]
  float* cfin = hfin + (size_t)B_DIM * 256;         // [B,H]

  char* ws = (char*)d_ws;
  float* gih = (float*)ws;
  float* W_ihT = (float*)(ws + 16777216);
  uint4* Whh_pack = (uint4*)(ws + 17825792);
  uint4* Wa_pack = (uint4*)(ws + 18350080);
  unsigned long long* ywp = (unsigned long long*)(ws + 18612224);
  unsigned long long* psx = (unsigned long long*)(ws + 19136512);

  pack_weights<<<1024, 256, 0, stream>>>(W_ih, W_hh, W_a, W_ihT, Whh_pack, Wa_pack, ywp, psx);
  compute_gih<<<512, 256, 0, stream>>>(embs, W_ihT, b_ih, b_hh, gih);
  alstm_rec<<<256, 512, 0, stream>>>(lens, gih, Whh_pack, Wa_pack, b_a, ywp, psx, out, hfin,
                                     cfin);
}